// Round 1
// baseline (1392.855 us; speedup 1.0000x reference)
//
#include <hip/hip_runtime.h>
#include <hip/hip_bf16.h>

// DeepSeek MoE layer: router(fp32) -> top2 -> grouped SwiGLU experts (bf16 MFMA) -> atomic combine
// B=4 S=2048 H=1024 I=256 E=256 TOPK=2 CAP=256; T=8192 tokens, N=16384 assignments.

#define T_TOK 8192
#define H_DIM 1024
#define I_DIM 256
#define E_NUM 256
#define CAPc  256

typedef short short8 __attribute__((ext_vector_type(8)));   // 8 x bf16 bits (4 VGPRs)
typedef float f32x4  __attribute__((ext_vector_type(4)));

__device__ __forceinline__ short f2b(float f) {             // fp32 -> bf16 (RNE)
    unsigned int u = __float_as_uint(f);
    u += 0x7FFFu + ((u >> 16) & 1u);
    return (short)(u >> 16);
}
__device__ __forceinline__ unsigned int pack2(float a, float b) {
    return (unsigned int)(unsigned short)f2b(a) | ((unsigned int)(unsigned short)f2b(b) << 16);
}

// ---------------- zero out + counters ----------------
__global__ void zero_kernel(float4* __restrict__ out4, int4* __restrict__ cnt4, int n4) {
    int idx = blockIdx.x * blockDim.x + threadIdx.x;
    if (idx < E_NUM / 4) cnt4[idx] = make_int4(0, 0, 0, 0);
    float4 z = make_float4(0.f, 0.f, 0.f, 0.f);
    int stride = gridDim.x * blockDim.x;
    for (int i = idx; i < n4; i += stride) out4[i] = z;
}

// ---------------- router GEMM: logits[T,E] = x[T,H] @ rw[E,H]^T (fp32) ----------------
// tile 128 tokens x 128 experts, 256 threads, 8x8 thread tile, BK=32
__global__ __launch_bounds__(256) void router_gemm(const float* __restrict__ x,
                                                   const float* __restrict__ rw,
                                                   float* __restrict__ logits) {
    __shared__ float xb[128 * 36];
    __shared__ float wb[128 * 36];
    const int tid = threadIdx.x;
    const int m0 = (int)(blockIdx.x >> 1) * 128;
    const int e0 = (int)(blockIdx.x & 1) * 128;
    const int tx = tid & 15, ty = tid >> 4;
    float acc[8][8];
#pragma unroll
    for (int i = 0; i < 8; ++i)
#pragma unroll
        for (int j = 0; j < 8; ++j) acc[i][j] = 0.f;

    const int r0 = tid >> 3, s4 = (tid & 7) * 4;
    for (int k0 = 0; k0 < H_DIM; k0 += 32) {
        __syncthreads();
#pragma unroll
        for (int p = 0; p < 4; ++p) {
            int r = p * 32 + r0;
            float4 vx = *(const float4*)&x[(size_t)(m0 + r) * H_DIM + k0 + s4];
            *(float4*)&xb[r * 36 + s4] = vx;
            float4 vw = *(const float4*)&rw[(size_t)(e0 + r) * H_DIM + k0 + s4];
            *(float4*)&wb[r * 36 + s4] = vw;
        }
        __syncthreads();
#pragma unroll
        for (int kk = 0; kk < 32; kk += 4) {
            float4 xr[8], wr[8];
#pragma unroll
            for (int i = 0; i < 8; ++i) xr[i] = *(const float4*)&xb[(ty + 16 * i) * 36 + kk];
#pragma unroll
            for (int j = 0; j < 8; ++j) wr[j] = *(const float4*)&wb[(tx + 16 * j) * 36 + kk];
#pragma unroll
            for (int i = 0; i < 8; ++i)
#pragma unroll
                for (int j = 0; j < 8; ++j)
                    acc[i][j] += xr[i].x * wr[j].x + xr[i].y * wr[j].y +
                                 xr[i].z * wr[j].z + xr[i].w * wr[j].w;
        }
    }
#pragma unroll
    for (int i = 0; i < 8; ++i)
#pragma unroll
        for (int j = 0; j < 8; ++j)
            logits[(size_t)(m0 + ty + 16 * i) * E_NUM + (e0 + tx + 16 * j)] = acc[i][j];
}

// ---------------- softmax + top2 + dispatch (one wave per token) ----------------
__global__ __launch_bounds__(256) void topk_kernel(const float* __restrict__ logits,
                                                   int* __restrict__ cnt,
                                                   int* __restrict__ tok_of,
                                                   float* __restrict__ wt_of) {
    const int t = blockIdx.x * 4 + (threadIdx.x >> 6);
    const int l = threadIdx.x & 63;
    float4 lv = *(const float4*)&logits[(size_t)t * E_NUM + l * 4];
    // max over 256
    float mx = fmaxf(fmaxf(lv.x, lv.y), fmaxf(lv.z, lv.w));
    for (int o = 32; o; o >>= 1) mx = fmaxf(mx, __shfl_xor(mx, o));
    // sum exp
    float se = __expf(lv.x - mx) + __expf(lv.y - mx) + __expf(lv.z - mx) + __expf(lv.w - mx);
    for (int o = 32; o; o >>= 1) se += __shfl_xor(se, o);
    // local top2 (value desc, index asc tiebreak like lax.top_k)
    float vals[4] = {lv.x, lv.y, lv.z, lv.w};
    float v1 = -3.4e38f, v2 = -3.4e38f;
    int i1 = 0x7fffffff, i2 = 0x7fffffff;
#pragma unroll
    for (int c = 0; c < 4; ++c) {
        float v = vals[c]; int idx = l * 4 + c;
        if (v > v1 || (v == v1 && idx < i1)) { v2 = v1; i2 = i1; v1 = v; i1 = idx; }
        else if (v > v2 || (v == v2 && idx < i2)) { v2 = v; i2 = idx; }
    }
    // butterfly merge of top2 pairs
    for (int o = 1; o < 64; o <<= 1) {
        float ov1 = __shfl_xor(v1, o); int oi1 = __shfl_xor(i1, o);
        float ov2 = __shfl_xor(v2, o); int oi2 = __shfl_xor(i2, o);
        if (ov1 > v1 || (ov1 == v1 && oi1 < i1)) {
            float nv2; int ni2;
            if (v1 > ov2 || (v1 == ov2 && i1 < oi2)) { nv2 = v1; ni2 = i1; }
            else { nv2 = ov2; ni2 = oi2; }
            v1 = ov1; i1 = oi1; v2 = nv2; i2 = ni2;
        } else {
            if (ov1 > v2 || (ov1 == v2 && oi1 < i2)) { v2 = ov1; i2 = oi1; }
        }
    }
    if (l == 0) {
        float p1 = __expf(v1 - mx) / se;
        float p2 = __expf(v2 - mx) / se;
        float ew = __expf(p2 - p1);               // scores = softmax([p1,p2])
        float w1 = 1.f / (1.f + ew);
        float w2 = ew / (1.f + ew);
        int s1 = atomicAdd(&cnt[i1], 1); if (s1 > CAPc - 1) s1 = CAPc - 1;
        tok_of[i1 * CAPc + s1] = t; wt_of[i1 * CAPc + s1] = w1;
        int s2 = atomicAdd(&cnt[i2], 1); if (s2 > CAPc - 1) s2 = CAPc - 1;
        tok_of[i2 * CAPc + s2] = t; wt_of[i2 * CAPc + s2] = w2;
    }
}

// ---------------- per-expert SwiGLU MLP, bf16 MFMA 16x16x32, block = 1 expert ----------------
// 512 threads = 8 waves. M-chunk 128 tokens. Gate+Up fused in one K pass (K=1024, BK=64),
// act stashed to LDS bf16, then down GEMM (K=256, N=1024), atomicAdd into out.
__global__ __launch_bounds__(512) void expert_kernel(
    const float* __restrict__ x, const float* __restrict__ wg, const float* __restrict__ wu,
    const float* __restrict__ wd, const float* __restrict__ gsc, const float* __restrict__ usc,
    const float* __restrict__ dsc, const int* __restrict__ cnt, const int* __restrict__ tok_of,
    const float* __restrict__ wt_of, float* __restrict__ out) {
    __shared__ short xs[128 * 72];      // 128 rows x 64 k (stride 72 shorts, 16B aligned rows)
    __shared__ short acts[128 * 264];   // 128 rows x 256 i (stride 264)
    __shared__ int   toks[128];
    __shared__ float wts[128];

    const int e = blockIdx.x;
    int c = cnt[e]; if (c > CAPc) c = CAPc;
    if (c == 0) return;
    const float gse = gsc[e], use_ = usc[e], dse = dsc[e];
    const int tid = threadIdx.x;
    const int w = tid >> 6, l = tid & 63, l15 = l & 15, lq = l >> 4;
    const size_t wbase = (size_t)e * H_DIM * I_DIM;

    for (int mc = 0; mc * 128 < c; ++mc) {
        const int rows = min(128, c - mc * 128);
        __syncthreads();
        if (tid < rows) {
            toks[tid] = tok_of[e * CAPc + mc * 128 + tid];
            wts[tid]  = wt_of[e * CAPc + mc * 128 + tid];
        }
        __syncthreads();

        // ---- fused gate + up over K=1024 ----
        f32x4 accg[8][2], accu[8][2];
        f32x4 z4 = {0.f, 0.f, 0.f, 0.f};
#pragma unroll
        for (int i = 0; i < 8; ++i)
#pragma unroll
            for (int j = 0; j < 2; ++j) { accg[i][j] = z4; accu[i][j] = z4; }

        const int l16 = tid & 15, g16 = tid >> 4;
        for (int ko = 0; ko < 16; ++ko) {
            __syncthreads();
#pragma unroll
            for (int gg = 0; gg < 4; ++gg) {
                int r = gg * 32 + g16;
                unsigned int lo = 0u, hi = 0u;
                if (r < rows) {
                    float4 v = *(const float4*)&x[(size_t)toks[r] * H_DIM + ko * 64 + l16 * 4];
                    lo = pack2(v.x, v.y); hi = pack2(v.z, v.w);
                }
                *(uint2*)&xs[r * 72 + l16 * 4] = make_uint2(lo, hi);
            }
            __syncthreads();
            for (int ki = 0; ki < 2; ++ki) {
                const int kk = ki * 32;
                short8 a[8];
#pragma unroll
                for (int mt = 0; mt < 8; ++mt)
                    a[mt] = *(const short8*)&xs[(mt * 16 + l15) * 72 + kk + lq * 8];
                const int kg = ko * 64 + kk + lq * 8;
#pragma unroll
                for (int nt = 0; nt < 2; ++nt) {
                    const int col = w * 32 + nt * 16 + l15;
                    const float* pg = wg + wbase + (size_t)kg * I_DIM + col;
                    const float* pu = wu + wbase + (size_t)kg * I_DIM + col;
                    short8 bg, bu;
#pragma unroll
                    for (int j = 0; j < 8; ++j) { bg[j] = f2b(pg[j * I_DIM]); bu[j] = f2b(pu[j * I_DIM]); }
#pragma unroll
                    for (int mt = 0; mt < 8; ++mt) {
                        accg[mt][nt] = __builtin_amdgcn_mfma_f32_16x16x32_bf16(a[mt], bg, accg[mt][nt], 0, 0, 0);
                        accu[mt][nt] = __builtin_amdgcn_mfma_f32_16x16x32_bf16(a[mt], bu, accu[mt][nt], 0, 0, 0);
                    }
                }
            }
        }
        // ---- epilogue: act = silu(gate*gs) * (up*us) -> LDS bf16 ----
        __syncthreads();
#pragma unroll
        for (int mt = 0; mt < 8; ++mt)
#pragma unroll
            for (int nt = 0; nt < 2; ++nt) {
                const int col = w * 32 + nt * 16 + l15;
#pragma unroll
                for (int r = 0; r < 4; ++r) {
                    const int row = mt * 16 + lq * 4 + r;
                    float g = accg[mt][nt][r] * gse;
                    float u = accu[mt][nt][r] * use_;
                    float s = g / (1.f + __expf(-g));
                    acts[row * 264 + col] = f2b(s * u);
                }
            }
        __syncthreads();

        // ---- down GEMM: Y[128,1024] = act[128,256] @ wd[e][256,1024] ----
        for (int nc = 0; nc < 2; ++nc) {
            const int hb = w * 128 + nc * 64;
            f32x4 acc[8][4];
#pragma unroll
            for (int i = 0; i < 8; ++i)
#pragma unroll
                for (int j = 0; j < 4; ++j) acc[i][j] = z4;
            for (int ki = 0; ki < 8; ++ki) {
                const int kk = ki * 32;
                short8 a[8];
#pragma unroll
                for (int mt = 0; mt < 8; ++mt)
                    a[mt] = *(const short8*)&acts[(mt * 16 + l15) * 264 + kk + lq * 8];
                const int kg = kk + lq * 8;
#pragma unroll
                for (int nt = 0; nt < 4; ++nt) {
                    const int col = hb + nt * 16 + l15;
                    const float* pd = wd + (size_t)e * I_DIM * H_DIM + (size_t)kg * H_DIM + col;
                    short8 b;
#pragma unroll
                    for (int j = 0; j < 8; ++j) b[j] = f2b(pd[j * H_DIM]);
#pragma unroll
                    for (int mt = 0; mt < 8; ++mt)
                        acc[mt][nt] = __builtin_amdgcn_mfma_f32_16x16x32_bf16(a[mt], b, acc[mt][nt], 0, 0, 0);
                }
            }
#pragma unroll
            for (int mt = 0; mt < 8; ++mt)
#pragma unroll
                for (int nt = 0; nt < 4; ++nt) {
                    const int col = hb + nt * 16 + l15;
#pragma unroll
                    for (int r = 0; r < 4; ++r) {
                        const int row = mt * 16 + lq * 4 + r;
                        if (row < rows) {
                            float v = acc[mt][nt][r] * dse * wts[row];
                            atomicAdd(&out[(size_t)toks[row] * H_DIM + col], v);
                        }
                    }
                }
        }
    }
}

extern "C" void kernel_launch(void* const* d_in, const int* in_sizes, int n_in,
                              void* d_out, int out_size, void* d_ws, size_t ws_size,
                              hipStream_t stream) {
    const float* x  = (const float*)d_in[0];
    const float* rw = (const float*)d_in[1];
    const float* wg = (const float*)d_in[2];
    const float* wu = (const float*)d_in[3];
    const float* wd = (const float*)d_in[4];
    const float* gs = (const float*)d_in[5];
    const float* us = (const float*)d_in[6];
    const float* ds = (const float*)d_in[7];
    float* out = (float*)d_out;

    char* ws = (char*)d_ws;
    float* logits = (float*)ws;                        // 8192*256*4 = 8388608 B
    int*   cnt    = (int*)(ws + 8388608);              // 1024 B
    int*   tok_of = (int*)(ws + 8389632);              // 256*256*4 = 262144 B
    float* wt_of  = (float*)(ws + 8651776);            // 262144 B

    zero_kernel<<<2048, 256, 0, stream>>>((float4*)out, (int4*)cnt, (T_TOK * H_DIM) / 4);
    router_gemm<<<128, 256, 0, stream>>>(x, rw, logits);
    topk_kernel<<<2048, 256, 0, stream>>>(logits, cnt, tok_of, wt_of);
    expert_kernel<<<E_NUM, 512, 0, stream>>>(x, wg, wu, wd, gs, us, ds, cnt, tok_of, wt_of, out);
}

// Round 2
// 1012.085 us; speedup vs baseline: 1.3762x; 1.3762x over previous
//
#include <hip/hip_runtime.h>
#include <hip/hip_bf16.h>

// DeepSeek MoE: router(fp32 vector GEMM) -> top2 -> grouped SwiGLU experts
// (bf16 MFMA, LDS-staged weights) -> per-assignment y_ws + combine (no atomics).
// B=4 S=2048 H=1024 I=256 E=256 K=2 CAP=256; T=8192 tokens, N=16384 assignments.

#define T_TOK 8192
#define H_DIM 1024
#define I_DIM 256
#define E_NUM 256
#define CAPc  256

typedef short short8 __attribute__((ext_vector_type(8)));   // 8 x bf16 bits
typedef float f32x4  __attribute__((ext_vector_type(4)));

__device__ __forceinline__ short f2b(float f) {             // fp32 -> bf16 (RNE)
    unsigned int u = __float_as_uint(f);
    u += 0x7FFFu + ((u >> 16) & 1u);
    return (short)(u >> 16);
}
__device__ __forceinline__ unsigned int pack2(float a, float b) {
    return (unsigned int)(unsigned short)f2b(a) | ((unsigned int)(unsigned short)f2b(b) << 16);
}

// ---------------- zeroing ----------------
__global__ void zero_cnt_kernel(int4* __restrict__ cnt4) {
    cnt4[threadIdx.x] = make_int4(0, 0, 0, 0);              // 64 threads x int4 = 256 ints
}
__global__ void zero_out_kernel(float4* __restrict__ out4, int n4) {
    int idx = blockIdx.x * blockDim.x + threadIdx.x;
    float4 z = make_float4(0.f, 0.f, 0.f, 0.f);
    int stride = gridDim.x * blockDim.x;
    for (int i = idx; i < n4; i += stride) out4[i] = z;
}

// ---------------- router GEMM: logits[T,E] = x[T,H] @ rw[E,H]^T (fp32) ----------------
// tile 64 tokens x 64 experts, 256 threads, 4x4 per-thread, BK=32. No spills (acc=16 fp32).
__global__ __launch_bounds__(256) void router_gemm(const float* __restrict__ x,
                                                   const float* __restrict__ rw,
                                                   float* __restrict__ logits) {
    __shared__ float xb[64 * 36];
    __shared__ float wb[64 * 36];
    const int tid = threadIdx.x;
    const int m0 = (int)(blockIdx.x >> 2) * 64;
    const int e0 = (int)(blockIdx.x & 3) * 64;
    const int tx = tid & 15, ty = tid >> 4;
    float acc[4][4];
#pragma unroll
    for (int i = 0; i < 4; ++i)
#pragma unroll
        for (int j = 0; j < 4; ++j) acc[i][j] = 0.f;

    const int r0 = tid >> 3, s4 = (tid & 7) * 4;
    for (int k0 = 0; k0 < H_DIM; k0 += 32) {
        __syncthreads();
#pragma unroll
        for (int p = 0; p < 2; ++p) {
            int r = p * 32 + r0;
            *(float4*)&xb[r * 36 + s4] = *(const float4*)&x[(size_t)(m0 + r) * H_DIM + k0 + s4];
            *(float4*)&wb[r * 36 + s4] = *(const float4*)&rw[(size_t)(e0 + r) * H_DIM + k0 + s4];
        }
        __syncthreads();
#pragma unroll 2
        for (int kk = 0; kk < 32; kk += 4) {
            float4 xr[4], wr[4];
#pragma unroll
            for (int i = 0; i < 4; ++i) xr[i] = *(const float4*)&xb[(ty + 16 * i) * 36 + kk];
#pragma unroll
            for (int j = 0; j < 4; ++j) wr[j] = *(const float4*)&wb[(tx + 16 * j) * 36 + kk];
#pragma unroll
            for (int i = 0; i < 4; ++i)
#pragma unroll
                for (int j = 0; j < 4; ++j)
                    acc[i][j] += xr[i].x * wr[j].x + xr[i].y * wr[j].y +
                                 xr[i].z * wr[j].z + xr[i].w * wr[j].w;
        }
    }
#pragma unroll
    for (int i = 0; i < 4; ++i)
#pragma unroll
        for (int j = 0; j < 4; ++j)
            logits[(size_t)(m0 + ty + 16 * i) * E_NUM + (e0 + tx + 16 * j)] = acc[i][j];
}

// ---------------- softmax + top2 + dispatch (one wave per token) ----------------
// tok_of stores PACKED assignment id a = 2*t + k (token = a>>1).
__global__ __launch_bounds__(256) void topk_kernel(const float* __restrict__ logits,
                                                   int* __restrict__ cnt,
                                                   int* __restrict__ tok_of,
                                                   float* __restrict__ wt_of) {
    const int t = blockIdx.x * 4 + (threadIdx.x >> 6);
    const int l = threadIdx.x & 63;
    float4 lv = *(const float4*)&logits[(size_t)t * E_NUM + l * 4];
    float mx = fmaxf(fmaxf(lv.x, lv.y), fmaxf(lv.z, lv.w));
    for (int o = 32; o; o >>= 1) mx = fmaxf(mx, __shfl_xor(mx, o));
    float se = __expf(lv.x - mx) + __expf(lv.y - mx) + __expf(lv.z - mx) + __expf(lv.w - mx);
    for (int o = 32; o; o >>= 1) se += __shfl_xor(se, o);
    float vals[4] = {lv.x, lv.y, lv.z, lv.w};
    float v1 = -3.4e38f, v2 = -3.4e38f;
    int i1 = 0x7fffffff, i2 = 0x7fffffff;
#pragma unroll
    for (int c = 0; c < 4; ++c) {
        float v = vals[c]; int idx = l * 4 + c;
        if (v > v1 || (v == v1 && idx < i1)) { v2 = v1; i2 = i1; v1 = v; i1 = idx; }
        else if (v > v2 || (v == v2 && idx < i2)) { v2 = v; i2 = idx; }
    }
    for (int o = 1; o < 64; o <<= 1) {
        float ov1 = __shfl_xor(v1, o); int oi1 = __shfl_xor(i1, o);
        float ov2 = __shfl_xor(v2, o); int oi2 = __shfl_xor(i2, o);
        if (ov1 > v1 || (ov1 == v1 && oi1 < i1)) {
            float nv2; int ni2;
            if (v1 > ov2 || (v1 == ov2 && i1 < oi2)) { nv2 = v1; ni2 = i1; }
            else { nv2 = ov2; ni2 = oi2; }
            v1 = ov1; i1 = oi1; v2 = nv2; i2 = ni2;
        } else {
            if (ov1 > v2 || (ov1 == v2 && oi1 < i2)) { v2 = ov1; i2 = oi1; }
        }
    }
    if (l == 0) {
        float p1 = __expf(v1 - mx) / se;
        float p2 = __expf(v2 - mx) / se;
        float ew = __expf(p2 - p1);               // softmax([p1,p2])
        float w1 = 1.f / (1.f + ew);
        float w2 = ew / (1.f + ew);
        int s1 = atomicAdd(&cnt[i1], 1); if (s1 > CAPc - 1) s1 = CAPc - 1;
        tok_of[i1 * CAPc + s1] = 2 * t;     wt_of[i1 * CAPc + s1] = w1;
        int s2 = atomicAdd(&cnt[i2], 1); if (s2 > CAPc - 1) s2 = CAPc - 1;
        tok_of[i2 * CAPc + s2] = 2 * t + 1; wt_of[i2 * CAPc + s2] = w2;
    }
}

// ---------------- per-expert SwiGLU MLP, bf16 MFMA 16x16x32, block = 1 expert ----------------
// 512 threads = 8 waves. M=128. Weights staged fp32->bf16 through LDS (coalesced dwordx4).
// Phase1: gate+up fused, K=1024, BK=32. Phase2: down, K=256, BK=32, 2 column-halves of 512.
// LDS unions: [xs|wgs|wus] (phase1) aliased by acts (phase1.5+2); wds separate; ~100 KB total.
__global__ __launch_bounds__(512, 2) void expert_kernel(
    const float* __restrict__ x, const float* __restrict__ wg, const float* __restrict__ wu,
    const float* __restrict__ wd, const float* __restrict__ gsc, const float* __restrict__ usc,
    const float* __restrict__ dsc, const int* __restrict__ cnt, const int* __restrict__ tok_of,
    const float* __restrict__ wt_of, float* __restrict__ out, float* __restrict__ y_ws,
    const int use_ws) {
    __shared__ __attribute__((aligned(16))) char lds[102400];
    short* xs   = (short*)(lds);            // [128][40]  bf16  phase1   (10240 B)
    short* wgs  = (short*)(lds + 10240);    // [32][272]  bf16  phase1   (17408 B)
    short* wus  = (short*)(lds + 27648);    // [32][272]  bf16  phase1   (17408 B)
    short* acts = (short*)(lds);            // [128][264] bf16  ph1.5+2  (67584 B, aliases above)
    short* wds  = (short*)(lds + 67584);    // [32][528]  bf16  phase2   (33792 B)
    int*   toks = (int*)(lds + 101376);     // [128]
    float* wts  = (float*)(lds + 101888);   // [128]

    const int e = blockIdx.x;
    int c = cnt[e]; if (c > CAPc) c = CAPc;
    if (c == 0) return;
    const float gse = gsc[e], use_ = usc[e], dse = dsc[e];
    const int tid = threadIdx.x;
    const int w = tid >> 6, l = tid & 63, l15 = l & 15, lq = l >> 4;
    const size_t wbase = (size_t)e * (H_DIM * I_DIM);
    const f32x4 z4 = {0.f, 0.f, 0.f, 0.f};

    for (int mc = 0; mc * 128 < c; ++mc) {
        const int rows = min(128, c - mc * 128);
        __syncthreads();
        if (tid < rows) {
            toks[tid] = tok_of[e * CAPc + mc * 128 + tid];
            wts[tid]  = wt_of[e * CAPc + mc * 128 + tid];
        }
        __syncthreads();

        // ---- phase 1: gate+up fused over K=1024, BK=32 ----
        f32x4 accg[8][2], accu[8][2];
#pragma unroll
        for (int i = 0; i < 8; ++i)
#pragma unroll
            for (int j = 0; j < 2; ++j) { accg[i][j] = z4; accu[i][j] = z4; }

        const int xr0 = tid >> 3, xc4 = (tid & 7) * 4;      // x staging: 8 threads/row
        const int r1 = xr0, r2 = 64 + xr0;
        const size_t xb1 = (r1 < rows) ? (size_t)(toks[r1] >> 1) * H_DIM : 0;
        const size_t xb2 = (r2 < rows) ? (size_t)(toks[r2] >> 1) * H_DIM : 0;
        const bool v1 = (r1 < rows), v2 = (r2 < rows);

        for (int ko = 0; ko < 32; ++ko) {
            __syncthreads();
            {   // x tile: 128 x 32 fp32 -> bf16
                unsigned int lo = 0, hi = 0;
                if (v1) { float4 v = *(const float4*)&x[xb1 + ko * 32 + xc4];
                          lo = pack2(v.x, v.y); hi = pack2(v.z, v.w); }
                *(uint2*)&xs[r1 * 40 + xc4] = make_uint2(lo, hi);
                lo = 0; hi = 0;
                if (v2) { float4 v = *(const float4*)&x[xb2 + ko * 32 + xc4];
                          lo = pack2(v.x, v.y); hi = pack2(v.z, v.w); }
                *(uint2*)&xs[r2 * 40 + xc4] = make_uint2(lo, hi);
            }
#pragma unroll
            for (int s = 0; s < 4; ++s) {   // wg/wu tiles: 32 x 256 fp32 each
                int f4 = s * 512 + tid;
                int k = f4 >> 6, c4 = (f4 & 63) * 4;
                size_t ga = wbase + (size_t)(ko * 32 + k) * I_DIM + c4;
                float4 vg = *(const float4*)&wg[ga];
                float4 vu = *(const float4*)&wu[ga];
                *(uint2*)&wgs[k * 272 + c4] = make_uint2(pack2(vg.x, vg.y), pack2(vg.z, vg.w));
                *(uint2*)&wus[k * 272 + c4] = make_uint2(pack2(vu.x, vu.y), pack2(vu.z, vu.w));
            }
            __syncthreads();
            short8 a[8];
#pragma unroll
            for (int mt = 0; mt < 8; ++mt)
                a[mt] = *(const short8*)&xs[(mt * 16 + l15) * 40 + lq * 8];
#pragma unroll
            for (int nt = 0; nt < 2; ++nt) {
                const int col = w * 32 + nt * 16 + l15;
                short8 bg, bu;
#pragma unroll
                for (int j = 0; j < 8; ++j) {
                    bg[j] = wgs[(lq * 8 + j) * 272 + col];
                    bu[j] = wus[(lq * 8 + j) * 272 + col];
                }
#pragma unroll
                for (int mt = 0; mt < 8; ++mt) {
                    accg[mt][nt] = __builtin_amdgcn_mfma_f32_16x16x32_bf16(a[mt], bg, accg[mt][nt], 0, 0, 0);
                    accu[mt][nt] = __builtin_amdgcn_mfma_f32_16x16x32_bf16(a[mt], bu, accu[mt][nt], 0, 0, 0);
                }
            }
        }

        // ---- phase 1.5: act = silu(g*gs)*(u*us) -> acts (aliases phase-1 buffers) ----
        __syncthreads();
#pragma unroll
        for (int mt = 0; mt < 8; ++mt)
#pragma unroll
            for (int nt = 0; nt < 2; ++nt) {
                const int col = w * 32 + nt * 16 + l15;
#pragma unroll
                for (int r = 0; r < 4; ++r) {
                    const int row = mt * 16 + lq * 4 + r;
                    float g = accg[mt][nt][r] * gse;
                    float u = accu[mt][nt][r] * use_;
                    acts[row * 264 + col] = f2b((g / (1.f + __expf(-g))) * u);
                }
            }

        // ---- phase 2: down GEMM, K=256, two column-halves of 512 ----
        for (int half = 0; half < 2; ++half) {
            f32x4 acc[8][4];
#pragma unroll
            for (int i = 0; i < 8; ++i)
#pragma unroll
                for (int j = 0; j < 4; ++j) acc[i][j] = z4;
            for (int ki = 0; ki < 8; ++ki) {
                __syncthreads();
#pragma unroll
                for (int s = 0; s < 8; ++s) {   // wd tile: 32 x 512 fp32
                    int f4 = s * 512 + tid;
                    int k = f4 >> 7, c4 = (f4 & 127) * 4;
                    float4 v = *(const float4*)&wd[(size_t)e * (I_DIM * H_DIM) +
                                                   (size_t)(ki * 32 + k) * H_DIM + half * 512 + c4];
                    *(uint2*)&wds[k * 528 + c4] = make_uint2(pack2(v.x, v.y), pack2(v.z, v.w));
                }
                __syncthreads();
                short8 a[8];
#pragma unroll
                for (int mt = 0; mt < 8; ++mt)
                    a[mt] = *(const short8*)&acts[(mt * 16 + l15) * 264 + ki * 32 + lq * 8];
#pragma unroll
                for (int nt = 0; nt < 4; ++nt) {
                    const int coll = w * 64 + nt * 16 + l15;
                    short8 b;
#pragma unroll
                    for (int j = 0; j < 8; ++j) b[j] = wds[(lq * 8 + j) * 528 + coll];
#pragma unroll
                    for (int mt = 0; mt < 8; ++mt)
                        acc[mt][nt] = __builtin_amdgcn_mfma_f32_16x16x32_bf16(a[mt], b, acc[mt][nt], 0, 0, 0);
                }
            }
#pragma unroll
            for (int mt = 0; mt < 8; ++mt)
#pragma unroll
                for (int r = 0; r < 4; ++r) {
                    const int row = mt * 16 + lq * 4 + r;
                    if (row < rows) {
                        const float wrow = dse * wts[row];
                        const int tk = toks[row];
#pragma unroll
                        for (int nt = 0; nt < 4; ++nt) {
                            const int col = half * 512 + w * 64 + nt * 16 + l15;
                            float v = acc[mt][nt][r] * wrow;
                            if (use_ws) y_ws[(size_t)tk * H_DIM + col] = v;
                            else atomicAdd(&out[(size_t)(tk >> 1) * H_DIM + col], v);
                        }
                    }
                }
        }
    }
}

// ---------------- combine: out[t] = y_ws[2t] + y_ws[2t+1] ----------------
__global__ __launch_bounds__(256) void combine_kernel(const float4* __restrict__ y4,
                                                      float4* __restrict__ out4) {
    const int t = blockIdx.x;
    const int i = threadIdx.x;
    float4 a = y4[(size_t)t * 512 + i];
    float4 b = y4[(size_t)t * 512 + 256 + i];
    out4[(size_t)t * 256 + i] = make_float4(a.x + b.x, a.y + b.y, a.z + b.z, a.w + b.w);
}

extern "C" void kernel_launch(void* const* d_in, const int* in_sizes, int n_in,
                              void* d_out, int out_size, void* d_ws, size_t ws_size,
                              hipStream_t stream) {
    const float* x  = (const float*)d_in[0];
    const float* rw = (const float*)d_in[1];
    const float* wg = (const float*)d_in[2];
    const float* wu = (const float*)d_in[3];
    const float* wd = (const float*)d_in[4];
    const float* gs = (const float*)d_in[5];
    const float* us = (const float*)d_in[6];
    const float* ds = (const float*)d_in[7];
    float* out = (float*)d_out;

    char* ws = (char*)d_ws;
    float* logits = (float*)ws;                        // 8192*256*4 = 8388608 B
    int*   cnt    = (int*)(ws + 8388608);              // 1024 B (pad to 1024)
    int*   tok_of = (int*)(ws + 8389632);              // 262144 B
    float* wt_of  = (float*)(ws + 8651776);            // 262144 B
    float* y_ws   = (float*)(ws + 8913920);            // 16384*1024*4 = 67108864 B
    const size_t need = 8913920ull + 67108864ull;
    const int use_ws = (ws_size >= need) ? 1 : 0;

    zero_cnt_kernel<<<1, 64, 0, stream>>>((int4*)cnt);
    if (!use_ws)
        zero_out_kernel<<<2048, 256, 0, stream>>>((float4*)out, (T_TOK * H_DIM) / 4);
    router_gemm<<<512, 256, 0, stream>>>(x, rw, logits);
    topk_kernel<<<2048, 256, 0, stream>>>(logits, cnt, tok_of, wt_of);
    expert_kernel<<<E_NUM, 512, 0, stream>>>(x, wg, wu, wd, gs, us, ds, cnt, tok_of, wt_of,
                                             out, y_ws, use_ws);
    if (use_ws)
        combine_kernel<<<T_TOK, 256, 0, stream>>>((const float4*)y_ws, (float4*)out);
}